// Round 3
// baseline (272.471 us; speedup 1.0000x reference)
//
#include <hip/hip_runtime.h>

#define OUT_W 1024
#define OUT_H 1024
#define BOXES_PER_BLOCK 16

typedef float f32x4 __attribute__((ext_vector_type(4)));

// 256 threads/block; each block processes BOXES_PER_BLOCK consecutive boxes.
// Per box, each thread writes one float4 of vector_x and one of vector_y.
// Loop iterations are independent -> compiler pipelines the uniform param
// loads for box k+1 against the stores of box k; each wave issues 32
// back-to-back dwordx4 stores (128 KiB/block), keeping the write path full.
__global__ __launch_bounds__(256)
void gv_kernel(const float* __restrict__ center,
               const float* __restrict__ wh,
               float* __restrict__ out_x,
               float* __restrict__ out_y,
               int bn_total)
{
    const int t   = threadIdx.x;
    const int bn0 = blockIdx.x * BOXES_PER_BLOCK;
    const int p0  = t * 4;

#pragma unroll 4
    for (int k = 0; k < BOXES_PER_BLOCK; ++k) {
        const int bn = bn0 + k;
        if (bn >= bn_total) break;

        // uniform 8B loads -> scalarized
        const float2 c = reinterpret_cast<const float2*>(center)[bn];
        const float2 w = reinterpret_cast<const float2*>(wh)[bn];
        const float cx = c.x, cy = c.y, Wb = w.x, Hb = w.y;

        // ks = floor(W/2)*2 - 1 ; r = floor((ks-1)/2) ; sigma = floor(r/3)
        const float ksw = floorf(Wb * 0.5f) * 2.0f - 1.0f;
        const float rw  = floorf((ksw - 1.0f) * 0.5f);
        const float sw  = floorf(rw / 3.0f);
        const float ksh = floorf(Hb * 0.5f) * 2.0f - 1.0f;
        const float rh  = floorf((ksh - 1.0f) * 0.5f);
        const float sh  = floorf(rh / 3.0f);

        const bool zero_box = ((cx + cy) + (Wb + Hb)) == 0.0f;

        // SCALE = 1.0 ; trunc toward zero (astype(int32))
        const float x = truncf(cx);
        const float y = truncf(cy);

        const float ul0 = x - rw;
        const float ul1 = y - rh;
        const float br0 = x + rw + 1.0f;
        const float br1 = y + rh + 1.0f;

        const bool in_ul = (ul0 >= 0.0f) && (ul0 <= (float)OUT_W) &&
                           (ul1 >= 0.0f) && (ul1 <= (float)OUT_H);
        const bool in_br = (br0 >= 0.0f) && (br0 <= (float)OUT_W) &&
                           (br1 >= 0.0f) && (br1 <= (float)OUT_H);
        const bool active = (!zero_box) && (sw != 0.0f) && (sh != 0.0f) && (in_ul || in_br);

        const float ssw = (sw == 0.0f) ? 1.0f : sw;
        const float ssh = (sh == 0.0f) ? 1.0f : sh;
        const float iw  = -1.0f / (2.0f * ssw * ssw);
        const float ih  = -1.0f / (2.0f * ssh * ssh);

        f32x4 rx, ry;
#pragma unroll
        for (int i = 0; i < 4; ++i) {
            const float p  = (float)(p0 + i);
            const float dx = p - x;
            const float dy = p - y;
            const bool mx = active && (p >= ul0) && (p < br0);
            const bool my = active && (p >= ul1) && (p < br1);
            rx[i] = mx ? __expf(dx * dx * iw) : 0.0f;
            ry[i] = my ? __expf(dy * dy * ih) : 0.0f;
        }

        const size_t row = (size_t)bn * (OUT_W / 4) + t;
        __builtin_nontemporal_store(rx, reinterpret_cast<f32x4*>(out_x) + row);
        __builtin_nontemporal_store(ry, reinterpret_cast<f32x4*>(out_y) + row);
    }
}

extern "C" void kernel_launch(void* const* d_in, const int* in_sizes, int n_in,
                              void* d_out, int out_size, void* d_ws, size_t ws_size,
                              hipStream_t stream) {
    const float* center = (const float*)d_in[0];  // [B,N,2]
    const float* wh     = (const float*)d_in[1];  // [B,N,2]
    float* out = (float*)d_out;                   // vector_x ++ vector_y, fp32

    const int BN = in_sizes[0] / 2;               // B*N = 32768
    float* out_x = out;
    float* out_y = out + (size_t)BN * OUT_W;

    const int grid = (BN + BOXES_PER_BLOCK - 1) / BOXES_PER_BLOCK;
    gv_kernel<<<dim3(grid), dim3(256), 0, stream>>>(center, wh, out_x, out_y, BN);
}

// Round 4
// 253.496 us; speedup vs baseline: 1.0749x; 1.0749x over previous
//
#include <hip/hip_runtime.h>

#define OUT_W 1024
#define OUT_H 1024

typedef float f32x4 __attribute__((ext_vector_type(4)));

// One block per (b,n) box, 256 threads; thread t covers elements [4t, 4t+4)
// of both the vector_x row and the vector_y row.
// Key opt: boxes_wh in [20,200) -> radius <= 99 -> nonzero span <= 199 of
// 1024 elements. A lane whose 4-chunk doesn't intersect the span stores
// zeros and skips all exp/cmp math; whole waves outside the span skip via
// s_cbranch_execz. ~64% of waves take the zero-only fast path.
__global__ __launch_bounds__(256)
void gv_kernel(const float* __restrict__ center,
               const float* __restrict__ wh,
               float* __restrict__ out_x,
               float* __restrict__ out_y)
{
    const int bn = blockIdx.x;
    const int t  = threadIdx.x;

    const float2 c = reinterpret_cast<const float2*>(center)[bn];
    const float2 w = reinterpret_cast<const float2*>(wh)[bn];
    const float cx = c.x, cy = c.y, Wb = w.x, Hb = w.y;

    // ks = floor(W/2)*2 - 1 ; r = floor((ks-1)/2) ; sigma = floor(r/3)
    const float ksw = floorf(Wb * 0.5f) * 2.0f - 1.0f;
    const float rw  = floorf((ksw - 1.0f) * 0.5f);
    const float sw  = floorf(rw / 3.0f);
    const float ksh = floorf(Hb * 0.5f) * 2.0f - 1.0f;
    const float rh  = floorf((ksh - 1.0f) * 0.5f);
    const float sh  = floorf(rh / 3.0f);

    const bool zero_box = ((cx + cy) + (Wb + Hb)) == 0.0f;

    // SCALE = 1.0 ; trunc toward zero (astype(int32))
    const float x = truncf(cx);
    const float y = truncf(cy);

    const float ul0 = x - rw;
    const float ul1 = y - rh;
    const float br0 = x + rw + 1.0f;
    const float br1 = y + rh + 1.0f;

    const bool in_ul = (ul0 >= 0.0f) && (ul0 <= (float)OUT_W) &&
                       (ul1 >= 0.0f) && (ul1 <= (float)OUT_H);
    const bool in_br = (br0 >= 0.0f) && (br0 <= (float)OUT_W) &&
                       (br1 >= 0.0f) && (br1 <= (float)OUT_H);
    const bool active = (!zero_box) && (sw != 0.0f) && (sh != 0.0f) && (in_ul || in_br);

    const float ssw = (sw == 0.0f) ? 1.0f : sw;
    const float ssh = (sh == 0.0f) ? 1.0f : sh;
    const float iw  = -1.0f / (2.0f * ssw * ssw);
    const float ih  = -1.0f / (2.0f * ssh * ssh);

    const float pf = (float)(t * 4);

    f32x4 rx = {0.0f, 0.0f, 0.0f, 0.0f};
    f32x4 ry = {0.0f, 0.0f, 0.0f, 0.0f};

    // x-row: only lanes whose 4-chunk [pf, pf+4) intersects [ul0, br0)
    if (active && (pf < br0) && (pf + 4.0f > ul0)) {
#pragma unroll
        for (int i = 0; i < 4; ++i) {
            const float p  = pf + (float)i;
            const float dx = p - x;
            const float g  = __expf(dx * dx * iw);
            rx[i] = ((p >= ul0) && (p < br0)) ? g : 0.0f;
        }
    }
    // y-row: same for [ul1, br1)
    if (active && (pf < br1) && (pf + 4.0f > ul1)) {
#pragma unroll
        for (int i = 0; i < 4; ++i) {
            const float p  = pf + (float)i;
            const float dy = p - y;
            const float g  = __expf(dy * dy * ih);
            ry[i] = ((p >= ul1) && (p < br1)) ? g : 0.0f;
        }
    }

    const size_t row = (size_t)bn * (OUT_W / 4) + t;
    reinterpret_cast<f32x4*>(out_x)[row] = rx;
    reinterpret_cast<f32x4*>(out_y)[row] = ry;
}

extern "C" void kernel_launch(void* const* d_in, const int* in_sizes, int n_in,
                              void* d_out, int out_size, void* d_ws, size_t ws_size,
                              hipStream_t stream) {
    const float* center = (const float*)d_in[0];  // [B,N,2]
    const float* wh     = (const float*)d_in[1];  // [B,N,2]
    float* out = (float*)d_out;                   // vector_x ++ vector_y, fp32

    const int BN = in_sizes[0] / 2;               // B*N = 32768
    float* out_x = out;
    float* out_y = out + (size_t)BN * OUT_W;

    gv_kernel<<<dim3(BN), dim3(256), 0, stream>>>(center, wh, out_x, out_y);
}